// Round 8
// baseline (338.999 us; speedup 1.0000x reference)
//
#include <hip/hip_runtime.h>
#include <stdint.h>

typedef __attribute__((ext_vector_type(8))) short s16x8;
typedef __attribute__((ext_vector_type(8))) _Float16 h16x8;
typedef __attribute__((ext_vector_type(4))) float f32x4;

__device__ __forceinline__ unsigned short f2h_bits(float f) {
  union { _Float16 h; unsigned short u; } cv;
  cv.h = (_Float16)f;
  return cv.u;
}
__device__ __forceinline__ f32x4 mfma16h(h16x8 a, h16x8 b, f32x4 c) {
  return __builtin_amdgcn_mfma_f32_16x16x32_f16(a, b, c, 0, 0, 0);
}
__device__ __forceinline__ h16x8 cvt8(float4 x, float4 y) {
  h16x8 r;
  r[0] = (_Float16)x.x; r[1] = (_Float16)x.y; r[2] = (_Float16)x.z; r[3] = (_Float16)x.w;
  r[4] = (_Float16)y.x; r[5] = (_Float16)y.y; r[6] = (_Float16)y.z; r[7] = (_Float16)y.w;
  return r;
}
__device__ __forceinline__ h16x8 cvt8s(float4 x, float4 y, float4 u, float4 v) {
  h16x8 r;
  r[0] = (_Float16)(x.x + u.x); r[1] = (_Float16)(x.y + u.y);
  r[2] = (_Float16)(x.z + u.z); r[3] = (_Float16)(x.w + u.w);
  r[4] = (_Float16)(y.x + v.x); r[5] = (_Float16)(y.y + v.y);
  r[6] = (_Float16)(y.z + v.z); r[7] = (_Float16)(y.w + v.w);
  return r;
}

// Vq write: thread owns quarter-local e-rows (ep2, ep2+1) x t-range tg*8..+7.
// Buf layout [64 e][64 t] f16, byte = e*128 + ((2t) ^ (((e>>1)&7)<<4)).  8 KB.
__device__ __forceinline__ void write_vq(char* VqB, int ep2, int tg, const float2* g) {
  s16x8 lo, hi;
#pragma unroll
  for (int j = 0; j < 8; ++j) {
    lo[j] = (short)f2h_bits(g[j].x);
    hi[j] = (short)f2h_bits(g[j].y);
  }
  int sw = ((ep2 >> 1) & 7) << 4;
  *(s16x8*)(VqB + ep2 * 128 + ((16 * tg) ^ sw)) = lo;
  *(s16x8*)(VqB + (ep2 + 1) * 128 + ((16 * tg) ^ sw)) = hi;
}

#define GATH(arr, Vsrc, qq)                                            \
  _Pragma("unroll") for (int j = 0; j < 8; ++j) arr[j] =               \
      *(const float2*)((Vsrc) + (tg * 8 + j) * 256 + (qq)*64 + ep2);

// ---------------- attention kernel: TWO batches per block ----------------
// QK interleaves batch A/B loads+MFMAs (2x independent loads per issue window).
// LDS 32768: Vq dbuf 2 x 8 KB @0/@8192, P_A @16384, P_B @24576.
// PV: 8 quarters (A0..A3,B0..B3), dbuf, gathers pipelined ~3 quarters ahead
// through two statically-named register arrays (parity: arrA=even, arrB=odd).
__global__ __launch_bounds__(256) void attn_kernel(
    const float* __restrict__ Vg, const float* __restrict__ Kg,
    const float* __restrict__ Qg, float* __restrict__ attn_out,
    unsigned short* __restrict__ xb /* f16 x = attn+q, may be null */) {
  __shared__ __align__(16) char smem[32768];
  char* PLA = smem + 16384;
  char* PLB2 = smem + 24576;

  const int b0 = blockIdx.x * 2;
  const int tid = threadIdx.x;
  const int lane = tid & 63;
  const int w = tid >> 6;  // wave id: owns S/A rows 16w..16w+15
  const int n = lane & 15;
  const int q = lane >> 4;

  const float* QA = Qg + (size_t)b0 * 64 * 256;
  const float* KA = Kg + (size_t)b0 * 64 * 256;
  const float* VA = Vg + (size_t)b0 * 64 * 256;
  const float* QB = QA + 64 * 256;
  const float* KB = KA + 64 * 256;
  const float* VB = VA + 64 * 256;

  const int ep2 = (tid & 31) * 2;  // V staging: e-pair within a 64-col quarter
  const int tg = tid >> 5;         // 0..7: t = tg*8..tg*8+7

  f32x4 sA[4], sB[4];
#pragma unroll
  for (int c = 0; c < 4; ++c) {
    sA[c] = f32x4{0.f, 0.f, 0.f, 0.f};
    sB[c] = f32x4{0.f, 0.f, 0.f, 0.f};
  }

  // ---- S = Q K^T for BOTH batches, interleaved at the kk level ----
#pragma unroll
  for (int ph = 0; ph < 2; ++ph) {
#pragma unroll
    for (int kk = 0; kk < 4; ++kk) {
      const int cb = ph * 128 + kk * 32 + q * 8;
      const float* qa = QA + (16 * w + n) * 256 + cb;
      const float* qb = QB + (16 * w + n) * 256 + cb;
      float4 a0 = *(const float4*)qa, a1 = *(const float4*)(qa + 4);
      float4 e0 = *(const float4*)qb, e1 = *(const float4*)(qb + 4);
      float4 ka0[4], ka1[4], kb0[4], kb1[4];
#pragma unroll
      for (int c = 0; c < 4; ++c) {
        const float* ks = KA + (16 * c + n) * 256 + cb;
        ka0[c] = *(const float4*)ks;
        ka1[c] = *(const float4*)(ks + 4);
      }
#pragma unroll
      for (int c = 0; c < 4; ++c) {
        const float* ks = KB + (16 * c + n) * 256 + cb;
        kb0[c] = *(const float4*)ks;
        kb1[c] = *(const float4*)(ks + 4);
      }
      h16x8 qha = cvt8(a0, a1);
      h16x8 qhb = cvt8(e0, e1);
#pragma unroll
      for (int c = 0; c < 4; ++c) {
        sA[c] = mfma16h(qha, cvt8(ka0[c], ka1[c]), sA[c]);
        sB[c] = mfma16h(qhb, cvt8(kb0[c], kb1[c]), sB[c]);
      }
    }
  }

  // ---- V gathers for quarters 0,1 of batch A (hide under softmax) ----
  float2 arrA[8], arrB[8];
  GATH(arrA, VA, 0);
  GATH(arrB, VA, 1);

  // ---- in-register softmax for both batches ----
  const float scale = 0.125f;
  float pA[4][4], pB[4][4];
#pragma unroll
  for (int r = 0; r < 4; ++r) {
    float m = -1e30f;
#pragma unroll
    for (int c = 0; c < 4; ++c) m = fmaxf(m, sA[c][r]);
#pragma unroll
    for (int mk = 1; mk < 16; mk <<= 1) m = fmaxf(m, __shfl_xor(m, mk, 64));
    float s = 0.f;
#pragma unroll
    for (int c = 0; c < 4; ++c) {
      float e = __expf((sA[c][r] - m) * scale);
      pA[c][r] = e;
      s += e;
    }
#pragma unroll
    for (int mk = 1; mk < 16; mk <<= 1) s += __shfl_xor(s, mk, 64);
    float inv = 1.0f / s;
#pragma unroll
    for (int c = 0; c < 4; ++c) pA[c][r] *= inv;
  }
#pragma unroll
  for (int r = 0; r < 4; ++r) {
    float m = -1e30f;
#pragma unroll
    for (int c = 0; c < 4; ++c) m = fmaxf(m, sB[c][r]);
#pragma unroll
    for (int mk = 1; mk < 16; mk <<= 1) m = fmaxf(m, __shfl_xor(m, mk, 64));
    float s = 0.f;
#pragma unroll
    for (int c = 0; c < 4; ++c) {
      float e = __expf((sB[c][r] - m) * scale);
      pB[c][r] = e;
      s += e;
    }
#pragma unroll
    for (int mk = 1; mk < 16; mk <<= 1) s += __shfl_xor(s, mk, 64);
    float inv = 1.0f / s;
#pragma unroll
    for (int c = 0; c < 4; ++c) pB[c][r] *= inv;
  }

  // ---- P to LDS (f16) for both batches ----
#pragma unroll
  for (int r = 0; r < 4; ++r) {
    int row = 16 * w + 4 * q + r;
    int sw = (row & 7) << 4;
#pragma unroll
    for (int c = 0; c < 4; ++c) {
      *(unsigned short*)(PLA + row * 128 + ((2 * (16 * c + n)) ^ sw)) =
          f2h_bits(pA[c][r]);
      *(unsigned short*)(PLB2 + row * 128 + ((2 * (16 * c + n)) ^ sw)) =
          f2h_bits(pB[c][r]);
    }
  }

  // ---- stage quarter 0, refill arrA with quarter 2 ----
  write_vq(smem, ep2, tg, arrA);
  GATH(arrA, VA, 2);
  __syncthreads();

  // ---- PV over 8 quarters: i<4 -> batch A, else batch B ----
  f32x4 accA[4];
#pragma unroll
  for (int i = 0; i < 8; ++i) {
    char* bufc = smem + (i & 1) * 8192;
    const char* PL = (i < 4) ? PLA : PLB2;
#pragma unroll
    for (int c = 0; c < 4; ++c) accA[c] = f32x4{0.f, 0.f, 0.f, 0.f};
    __builtin_amdgcn_s_setprio(1);
#pragma unroll
    for (int ks = 0; ks < 2; ++ks) {
      const int cb = (ks * 32 + q * 8) * 2;
      h16x8 af = *(const h16x8*)(PL + (16 * w + n) * 128 + (cb ^ ((n & 7) << 4)));
#pragma unroll
      for (int c = 0; c < 4; ++c) {
        int row = 16 * c + n;
        h16x8 bf = *(const h16x8*)(bufc + row * 128 + (cb ^ (((row >> 1) & 7) << 4)));
        accA[c] = mfma16h(af, bf, accA[c]);
      }
    }
    __builtin_amdgcn_s_setprio(0);

    if (i < 7) {
      __syncthreads();  // all waves done reading buf[(i+1)&1] (two quarters ago)
      char* bufn = smem + ((i + 1) & 1) * 8192;
      if ((i + 1) & 1) write_vq(bufn, ep2, tg, arrB);
      else             write_vq(bufn, ep2, tg, arrA);
      // refill the just-consumed array with quarter i+3 (same parity)
      if (i + 3 < 8) {
        const float* src = (i + 3 < 4) ? VA : VB;
        const int qq = (i + 3) & 3;
        if ((i + 1) & 1) { GATH(arrB, src, qq); }
        else             { GATH(arrA, src, qq); }
      }
      __syncthreads();
    }

    // epilogue for this quarter (after barrier: overlaps next quarter's MFMAs)
    const float* Qe = (i < 4) ? QA : QB;
    const size_t bb = (size_t)((i < 4) ? b0 : b0 + 1);
    const int ql = i & 3;
#pragma unroll
    for (int r = 0; r < 4; ++r) {
      int t = 16 * w + 4 * q + r;
      const float* qrow = Qe + t * 256 + ql * 64;
      size_t base = (bb * 64 + t) * 256 + ql * 64;
#pragma unroll
      for (int c = 0; c < 4; ++c) {
        int e = 16 * c + n;
        float aval = accA[c][r];
        attn_out[base + e] = aval;
        if (xb) xb[base + e] = f2h_bits(aval + qrow[e]);
      }
    }
  }
}

// ---------------- W_ff fp32 -> f16 ----------------
__global__ __launch_bounds__(256) void w2b_kernel(const float* __restrict__ W,
                                                  unsigned short* __restrict__ Wb) {
  int i = blockIdx.x * 256 + threadIdx.x;  // one float4 each, grid covers exactly
  float4 v = ((const float4*)W)[i];
  ushort4 o;
  o.x = f2h_bits(v.x); o.y = f2h_bits(v.y); o.z = f2h_bits(v.z); o.w = f2h_bits(v.w);
  ((ushort4*)Wb)[i] = o;
}

// ---------------- FF GEMM: no LDS, no barriers ----------------
// Both MFMA operands are row-major fragment-aligned -> direct global->reg.
// 1D grid 512, XCD-chunked decode: each XCD gets 64 consecutive logical blocks
// (2 full (n,z) groups) so the shared 1 MB W panel stays L2-resident.
template <bool USE_XB>
__global__ __launch_bounds__(256) void ff_kernel(
    const unsigned short* __restrict__ xb, const float* __restrict__ attn,
    const float* __restrict__ query, const unsigned short* __restrict__ Wb,
    float* __restrict__ part) {
  const int tid = threadIdx.x;
  const int lane = tid & 63, w = tid >> 6, n = lane & 15, q = lane >> 4;
  const int p = blockIdx.x;
  const int l = (p & 7) * 64 + (p >> 3);  // bijective XCD-chunked remap
  const int m0 = (l & 31) * 64;
  const int n0 = ((l >> 5) & 3) * 64;
  const int z = l >> 7;
  const int k0 = z * 4096;

  f32x4 acc[4];
#pragma unroll
  for (int c = 0; c < 4; ++c) acc[c] = f32x4{0.f, 0.f, 0.f, 0.f};

  const size_t ar = (size_t)(m0 + 16 * w + n) * 16384 + k0 + q * 8;
  size_t br[4];
#pragma unroll
  for (int c = 0; c < 4; ++c) br[c] = (size_t)(n0 + 16 * c + n) * 16384 + k0 + q * 8;

#pragma unroll 4
  for (int kp = 0; kp < 4096; kp += 32) {
    h16x8 af;
    if (USE_XB) {
      af = *(const h16x8*)(xb + ar + kp);
    } else {
      const float* ap = attn + ar + kp;
      const float* qp = query + ar + kp;
      float4 x0 = *(const float4*)ap, x1 = *(const float4*)(ap + 4);
      float4 y0 = *(const float4*)qp, y1 = *(const float4*)(qp + 4);
      af = cvt8s(x0, x1, y0, y1);
    }
#pragma unroll
    for (int c = 0; c < 4; ++c) {
      h16x8 bf = *(const h16x8*)(Wb + br[c] + kp);
      acc[c] = mfma16h(af, bf, acc[c]);
    }
  }

#pragma unroll
  for (int r = 0; r < 4; ++r) {
    int m = m0 + 16 * w + 4 * q + r;
#pragma unroll
    for (int c = 0; c < 4; ++c) {
      int nn = n0 + 16 * c + n;
      part[((size_t)z * 2048 + m) * 256 + nn] = acc[c][r];
    }
  }
}

// ---------------- reduce K-split partials + bias + ReLU ----------------
__global__ __launch_bounds__(256) void relu_kernel(const float* __restrict__ part,
                                                   const float* __restrict__ bias,
                                                   float* __restrict__ out, int KS) {
  int idx = blockIdx.x * 256 + threadIdx.x;
  float s = bias[idx & 255];
  for (int ks = 0; ks < KS; ++ks) s += part[(size_t)ks * 2048 * 256 + idx];
  out[idx] = fmaxf(s, 0.f);
}

extern "C" void kernel_launch(void* const* d_in, const int* in_sizes, int n_in,
                              void* d_out, int out_size, void* d_ws, size_t ws_size,
                              hipStream_t stream) {
  const float* value = (const float*)d_in[0];
  const float* key   = (const float*)d_in[1];
  const float* query = (const float*)d_in[2];
  // d_in[3] = mask, unused by the block
  const float* W_ff  = (const float*)d_in[4];
  const float* b_ff  = (const float*)d_in[5];

  float* out  = (float*)d_out;
  float* attn = out + (size_t)2048 * 256;  // outputs: (out, attention) concatenated

  const int KS = 4;
  const size_t wb_bytes   = (size_t)256 * 16384 * 2;      // 8 MB f16 W
  const size_t part_bytes = (size_t)KS * 2048 * 256 * 4;  // 8 MB fp32 partials
  const size_t xb_bytes   = (size_t)2048 * 64 * 256 * 2;  // 64 MB f16 x
  unsigned short* Wb = (unsigned short*)d_ws;
  float* part = (float*)((char*)d_ws + wb_bytes);
  bool use_xb = ws_size >= wb_bytes + part_bytes + xb_bytes;
  unsigned short* xb =
      use_xb ? (unsigned short*)((char*)d_ws + wb_bytes + part_bytes) : nullptr;

  w2b_kernel<<<4096, 256, 0, stream>>>(W_ff, Wb);
  attn_kernel<<<1024, 256, 0, stream>>>(value, key, query, attn, xb);
  if (use_xb)
    ff_kernel<true><<<512, 256, 0, stream>>>(xb, nullptr, nullptr, Wb, part);
  else
    ff_kernel<false><<<512, 256, 0, stream>>>(nullptr, attn, query, Wb, part);
  relu_kernel<<<2048, 256, 0, stream>>>(part, b_ff, out, KS);
}

// Round 9
// 307.703 us; speedup vs baseline: 1.1017x; 1.1017x over previous
//
#include <hip/hip_runtime.h>
#include <stdint.h>

typedef __attribute__((ext_vector_type(8))) short s16x8;
typedef __attribute__((ext_vector_type(8))) _Float16 h16x8;
typedef __attribute__((ext_vector_type(4))) float f32x4;

__device__ __forceinline__ unsigned short f2h_bits(float f) {
  union { _Float16 h; unsigned short u; } cv;
  cv.h = (_Float16)f;
  return cv.u;
}
__device__ __forceinline__ f32x4 mfma16h(h16x8 a, h16x8 b, f32x4 c) {
  return __builtin_amdgcn_mfma_f32_16x16x32_f16(a, b, c, 0, 0, 0);
}
__device__ __forceinline__ h16x8 cvt8(float4 x, float4 y) {
  h16x8 r;
  r[0] = (_Float16)x.x; r[1] = (_Float16)x.y; r[2] = (_Float16)x.z; r[3] = (_Float16)x.w;
  r[4] = (_Float16)y.x; r[5] = (_Float16)y.y; r[6] = (_Float16)y.z; r[7] = (_Float16)y.w;
  return r;
}

// ============ kernel A: S = QK^T, softmax, P -> global (fragment layout) ============
// No __syncthreads. 8 KB LDS used wave-locally for the P fragment transpose.
// P global layout: chunk ((b*4+w)*2+ks) of 1024 B, lane's 16 B at lane*16.
__global__ __launch_bounds__(256) void qk_kernel(
    const float* __restrict__ Kg, const float* __restrict__ Qg,
    unsigned short* __restrict__ Pg) {
  __shared__ __align__(16) char PL[8192];

  const int b = blockIdx.x;
  const int tid = threadIdx.x;
  const int lane = tid & 63;
  const int w = tid >> 6;
  const int n = lane & 15;
  const int q = lane >> 4;

  const float* Qb = Qg + (size_t)b * 64 * 256;
  const float* Kb = Kg + (size_t)b * 64 * 256;

  f32x4 accS[4];
#pragma unroll
  for (int c = 0; c < 4; ++c) accS[c] = f32x4{0.f, 0.f, 0.f, 0.f};

#pragma unroll
  for (int ph = 0; ph < 2; ++ph) {
#pragma unroll
    for (int kk = 0; kk < 4; ++kk) {
      const int cb = ph * 128 + kk * 32 + q * 8;
      const float* qsrc = Qb + (16 * w + n) * 256 + cb;
      float4 q0 = *(const float4*)qsrc;
      float4 q1 = *(const float4*)(qsrc + 4);
      float4 k0[4], k1[4];
#pragma unroll
      for (int c = 0; c < 4; ++c) {
        const float* ksrc = Kb + (16 * c + n) * 256 + cb;
        k0[c] = *(const float4*)ksrc;
        k1[c] = *(const float4*)(ksrc + 4);
      }
      h16x8 qh = cvt8(q0, q1);
#pragma unroll
      for (int c = 0; c < 4; ++c)
        accS[c] = mfma16h(qh, cvt8(k0[c], k1[c]), accS[c]);
    }
  }

  // in-register softmax; lane holds S[16w+4q+r][16c+n] in accS[c][r]
  const float scale = 0.125f;
  float p[4][4];
#pragma unroll
  for (int r = 0; r < 4; ++r) {
    float m = -1e30f;
#pragma unroll
    for (int c = 0; c < 4; ++c) m = fmaxf(m, accS[c][r]);
#pragma unroll
    for (int mk = 1; mk < 16; mk <<= 1) m = fmaxf(m, __shfl_xor(m, mk, 64));
    float s = 0.f;
#pragma unroll
    for (int c = 0; c < 4; ++c) {
      float e = __expf((accS[c][r] - m) * scale);
      p[c][r] = e;
      s += e;
    }
#pragma unroll
    for (int mk = 1; mk < 16; mk <<= 1) s += __shfl_xor(s, mk, 64);
    float inv = 1.0f / s;
#pragma unroll
    for (int c = 0; c < 4; ++c) p[c][r] *= inv;
  }

  // wave-local LDS transpose to MFMA-A fragment order (rows 16w..16w+15 only)
#pragma unroll
  for (int r = 0; r < 4; ++r) {
    int row = 16 * w + 4 * q + r;
    int sw = (row & 7) << 4;
#pragma unroll
    for (int c = 0; c < 4; ++c)
      *(unsigned short*)(PL + row * 128 + ((2 * (16 * c + n)) ^ sw)) =
          f2h_bits(p[c][r]);
  }
  // read fragments back (same wave; lgkmcnt ordering), store coalesced
#pragma unroll
  for (int ks = 0; ks < 2; ++ks) {
    const int cb = (ks * 32 + q * 8) * 2;
    s16x8 af = *(const s16x8*)(PL + (16 * w + n) * 128 + (cb ^ ((n & 7) << 4)));
    *(s16x8*)(Pg + ((size_t)(b * 4 + w) * 2 + ks) * 512 + lane * 8) = af;
  }
}

// Vt write: absolute e-rows (e, e+1) x t-range tg*8..tg*8+7.
// Layout [256 e][64 t] f16, byte = e*128 + ((2t) ^ (((e>>1)&7)<<4)).
__device__ __forceinline__ void write_vq(char* base, int e, int tg, const float2* g) {
  s16x8 lo, hi;
#pragma unroll
  for (int j = 0; j < 8; ++j) {
    lo[j] = (short)f2h_bits(g[j].x);
    hi[j] = (short)f2h_bits(g[j].y);
  }
  int sw = ((e >> 1) & 7) << 4;
  *(s16x8*)(base + e * 128 + ((16 * tg) ^ sw)) = lo;
  *(s16x8*)(base + (e + 1) * 128 + ((16 * tg) ^ sw)) = hi;
}

// ============ kernel B: A = P V + epilogue (attn fp32, xb f16) ============
// 32 KB Vt, ONE barrier. All 32 V gathers issued at block entry (deep burst);
// P fragments are 2 coalesced 16-B loads per lane.
__global__ __launch_bounds__(256) void pv_kernel(
    const float* __restrict__ Vg, const float* __restrict__ Qg,
    const unsigned short* __restrict__ Pg, float* __restrict__ attn_out,
    unsigned short* __restrict__ xb /* may be null */) {
  __shared__ __align__(16) char Vt[32768];

  const int b = blockIdx.x;
  const int tid = threadIdx.x;
  const int lane = tid & 63;
  const int w = tid >> 6;
  const int n = lane & 15;
  const int q = lane >> 4;

  const float* Vb = Vg + (size_t)b * 64 * 256;
  const float* Qb = Qg + (size_t)b * 64 * 256;

  const int ep2 = (tid & 31) * 2;
  const int tg = tid >> 5;

  // issue everything up front: 32 V gathers + 2 P fragment loads
  float2 g0[8], g1[8], g2[8], g3[8];
#pragma unroll
  for (int j = 0; j < 8; ++j) g0[j] = *(const float2*)(Vb + (tg * 8 + j) * 256 + 0 + ep2);
#pragma unroll
  for (int j = 0; j < 8; ++j) g1[j] = *(const float2*)(Vb + (tg * 8 + j) * 256 + 64 + ep2);
#pragma unroll
  for (int j = 0; j < 8; ++j) g2[j] = *(const float2*)(Vb + (tg * 8 + j) * 256 + 128 + ep2);
#pragma unroll
  for (int j = 0; j < 8; ++j) g3[j] = *(const float2*)(Vb + (tg * 8 + j) * 256 + 192 + ep2);
  h16x8 af0 = *(const h16x8*)(Pg + ((size_t)(b * 4 + w) * 2 + 0) * 512 + lane * 8);
  h16x8 af1 = *(const h16x8*)(Pg + ((size_t)(b * 4 + w) * 2 + 1) * 512 + lane * 8);

  write_vq(Vt, 0 + ep2, tg, g0);
  write_vq(Vt, 64 + ep2, tg, g1);
  write_vq(Vt, 128 + ep2, tg, g2);
  write_vq(Vt, 192 + ep2, tg, g3);
  __syncthreads();

  f32x4 accA[4];
#pragma unroll
  for (int qi = 0; qi < 4; ++qi) {
#pragma unroll
    for (int c = 0; c < 4; ++c) accA[c] = f32x4{0.f, 0.f, 0.f, 0.f};
    __builtin_amdgcn_s_setprio(1);
#pragma unroll
    for (int ks = 0; ks < 2; ++ks) {
      const int cb = (ks * 32 + q * 8) * 2;
      h16x8 af = ks ? af1 : af0;
#pragma unroll
      for (int c = 0; c < 4; ++c) {
        int row = qi * 64 + 16 * c + n;
        h16x8 bf = *(const h16x8*)(Vt + row * 128 + (cb ^ (((row >> 1) & 7) << 4)));
        accA[c] = mfma16h(af, bf, accA[c]);
      }
    }
    __builtin_amdgcn_s_setprio(0);

#pragma unroll
    for (int r = 0; r < 4; ++r) {
      int t = 16 * w + 4 * q + r;
      const float* qrow = Qb + t * 256 + qi * 64;
      size_t base = ((size_t)b * 64 + t) * 256 + qi * 64;
#pragma unroll
      for (int c = 0; c < 4; ++c) {
        int e = 16 * c + n;
        float aval = accA[c][r];
        attn_out[base + e] = aval;
        if (xb) xb[base + e] = f2h_bits(aval + qrow[e]);
      }
    }
  }
}

// ---------------- W_ff fp32 -> f16 ----------------
__global__ __launch_bounds__(256) void w2b_kernel(const float* __restrict__ W,
                                                  unsigned short* __restrict__ Wb) {
  int i = blockIdx.x * 256 + threadIdx.x;
  float4 v = ((const float4*)W)[i];
  ushort4 o;
  o.x = f2h_bits(v.x); o.y = f2h_bits(v.y); o.z = f2h_bits(v.z); o.w = f2h_bits(v.w);
  ((ushort4*)Wb)[i] = o;
}

// ---------------- FF GEMM: out_part = x @ W^T, 64x64 tiles, K-split ----------------
// (round-5 version, the best-measured ff)
template <bool USE_XB>
__global__ __launch_bounds__(256) void ff_kernel(
    const unsigned short* __restrict__ xb, const float* __restrict__ attn,
    const float* __restrict__ query, const unsigned short* __restrict__ Wb,
    float* __restrict__ part, int kchunk) {
  __shared__ __align__(16) unsigned short As[64 * 72];
  __shared__ __align__(16) unsigned short Bs[64 * 72];
  const int tid = threadIdx.x;
  const int lane = tid & 63, w = tid >> 6, n = lane & 15, q = lane >> 4;
  const int m0 = blockIdx.x * 64;
  const int n0 = blockIdx.y * 64;
  const int k0 = blockIdx.z * kchunk;

  f32x4 acc[4];
#pragma unroll
  for (int c = 0; c < 4; ++c) acc[c] = f32x4{0.f, 0.f, 0.f, 0.f};

  const int srow = tid >> 3;  // 0..31
  const int scol = (tid & 7) * 8;

  for (int kk = 0; kk < kchunk; kk += 64) {
#pragma unroll
    for (int rr = 0; rr < 2; ++rr) {
      int row = rr * 32 + srow;
      size_t ga = (size_t)(m0 + row) * 16384 + k0 + kk + scol;
      if (USE_XB) {
        *(uint4*)(As + row * 72 + scol) = *(const uint4*)(xb + ga);
      } else {
        float4 a0 = *(const float4*)(attn + ga);
        float4 a1 = *(const float4*)(attn + ga + 4);
        float4 q0 = *(const float4*)(query + ga);
        float4 q1 = *(const float4*)(query + ga + 4);
        ushort4 h0, h1;
        h0.x = f2h_bits(a0.x + q0.x); h0.y = f2h_bits(a0.y + q0.y);
        h0.z = f2h_bits(a0.z + q0.z); h0.w = f2h_bits(a0.w + q0.w);
        h1.x = f2h_bits(a1.x + q1.x); h1.y = f2h_bits(a1.y + q1.y);
        h1.z = f2h_bits(a1.z + q1.z); h1.w = f2h_bits(a1.w + q1.w);
        *(ushort4*)(As + row * 72 + scol) = h0;
        *(ushort4*)(As + row * 72 + scol + 4) = h1;
      }
      size_t gw = (size_t)(n0 + row) * 16384 + k0 + kk + scol;
      *(uint4*)(Bs + row * 72 + scol) = *(const uint4*)(Wb + gw);
    }
    __syncthreads();
#pragma unroll
    for (int ks = 0; ks < 2; ++ks) {
      const int colb = ks * 32 + q * 8;
      h16x8 af = *(const h16x8*)(As + (16 * w + n) * 72 + colb);
#pragma unroll
      for (int c = 0; c < 4; ++c) {
        h16x8 bf = *(const h16x8*)(Bs + (16 * c + n) * 72 + colb);
        acc[c] = mfma16h(af, bf, acc[c]);
      }
    }
    __syncthreads();
  }
#pragma unroll
  for (int r = 0; r < 4; ++r) {
    int m = m0 + 16 * w + 4 * q + r;
#pragma unroll
    for (int c = 0; c < 4; ++c) {
      int nn = n0 + 16 * c + n;
      part[((size_t)blockIdx.z * 2048 + m) * 256 + nn] = acc[c][r];
    }
  }
}

// ---------------- reduce K-split partials + bias + ReLU ----------------
__global__ __launch_bounds__(256) void relu_kernel(const float* __restrict__ part,
                                                   const float* __restrict__ bias,
                                                   float* __restrict__ out, int KS) {
  int idx = blockIdx.x * 256 + threadIdx.x;
  float s = bias[idx & 255];
  for (int ks = 0; ks < KS; ++ks) s += part[(size_t)ks * 2048 * 256 + idx];
  out[idx] = fmaxf(s, 0.f);
}

extern "C" void kernel_launch(void* const* d_in, const int* in_sizes, int n_in,
                              void* d_out, int out_size, void* d_ws, size_t ws_size,
                              hipStream_t stream) {
  const float* value = (const float*)d_in[0];
  const float* key   = (const float*)d_in[1];
  const float* query = (const float*)d_in[2];
  // d_in[3] = mask, unused by the block
  const float* W_ff  = (const float*)d_in[4];
  const float* b_ff  = (const float*)d_in[5];

  float* out  = (float*)d_out;
  float* attn = out + (size_t)2048 * 256;  // outputs: (out, attention) concatenated

  const int KS = 4;
  const size_t wb_bytes   = (size_t)256 * 16384 * 2;      // 8 MB f16 W
  const size_t part_bytes = (size_t)KS * 2048 * 256 * 4;  // 8 MB fp32 partials
  const size_t p_bytes    = (size_t)2048 * 64 * 64 * 2;   // 16.8 MB f16 P
  const size_t xb_bytes   = (size_t)2048 * 64 * 256 * 2;  // 64 MB f16 x
  unsigned short* Wb = (unsigned short*)d_ws;
  float* part = (float*)((char*)d_ws + wb_bytes);
  unsigned short* Pg = (unsigned short*)((char*)d_ws + wb_bytes + part_bytes);
  bool use_xb = ws_size >= wb_bytes + part_bytes + p_bytes + xb_bytes;
  unsigned short* xbp =
      use_xb ? (unsigned short*)((char*)d_ws + wb_bytes + part_bytes + p_bytes)
             : nullptr;

  w2b_kernel<<<4096, 256, 0, stream>>>(W_ff, Wb);
  qk_kernel<<<2048, 256, 0, stream>>>(key, query, Pg);
  pv_kernel<<<2048, 256, 0, stream>>>(value, query, Pg, attn, xbp);
  dim3 gb(32, 4, KS);
  if (use_xb)
    ff_kernel<true><<<gb, 256, 0, stream>>>(xbp, nullptr, nullptr, Wb, part, 16384 / KS);
  else
    ff_kernel<false><<<gb, 256, 0, stream>>>(nullptr, attn, query, Wb, part, 16384 / KS);
  relu_kernel<<<2048, 256, 0, stream>>>(part, b_ff, out, KS);
}